// Round 14
// baseline (150.023 us; speedup 1.0000x reference)
//
#include <hip/hip_runtime.h>
#include <hip/hip_fp16.h>
#include <cfloat>
#include <cmath>
#include <cstdint>

#define NN 8192
#define DD 16
#define EPSF 1e-8f
#define CH2 16          // j-chunks of 512 (lean/drift)
#define CAPC 32         // LDS candidate slots per (row, chunk)
#define CAPR 384        // compact global candidate slots per row

typedef float4 f4;
typedef _Float16 f16x4 __attribute__((ext_vector_type(4)));
typedef _Float16 f16x2 __attribute__((ext_vector_type(2)));
typedef float f32x4 __attribute__((ext_vector_type(4)));

__device__ __forceinline__ unsigned umn(unsigned a, unsigned b) { return a < b ? a : b; }
__device__ __forceinline__ unsigned umx(unsigned a, unsigned b) { return a < b ? b : a; }

__device__ __forceinline__ uint32_t pkrtz(float a, float b) {
    return __builtin_bit_cast(uint32_t, __builtin_amdgcn_cvt_pkrtz(a, b));
}

__device__ __forceinline__ float fsqrt(float x) {
#if defined(__has_builtin) && __has_builtin(__builtin_amdgcn_sqrtf)
    return __builtin_amdgcn_sqrtf(x);
#else
    return sqrtf(x);
#endif
}

__device__ __forceinline__ float fexp2(float x) {
#if defined(__has_builtin) && __has_builtin(__builtin_amdgcn_exp2f)
    return __builtin_amdgcn_exp2f(x);
#else
    return exp2f(x);
#endif
}

__device__ __forceinline__ float fdot2a(uint32_t a, uint32_t b, float c) {
#if defined(__has_builtin) && __has_builtin(__builtin_amdgcn_fdot2)
    return __builtin_amdgcn_fdot2(__builtin_bit_cast(f16x2, a), __builtin_bit_cast(f16x2, b), c, false);
#else
    __half2 ah = __builtin_bit_cast(__half2, a), bh = __builtin_bit_cast(__half2, b);
    float2 af = __half22float2(ah), bf = __half22float2(bh);
    return fmaf(af.x, bf.x, fmaf(af.y, bf.y, c));
#endif
}

// ---------------- column-stat partials ----------------
__device__ __forceinline__ void colstat_reduce_store(const float h[DD], double* __restrict__ part,
                                                     int blk, int tid) {
    const int lane = tid & 63, wid = tid >> 6;
    double s[DD], s2[DD];
#pragma unroll
    for (int c = 0; c < DD; c++) { double a = (double)h[c]; s[c] = a; s2[c] = a * a; }
#pragma unroll
    for (int c = 0; c < DD; c++) {
#pragma unroll
        for (int off = 1; off < 64; off <<= 1) {
            s[c] += __shfl_xor(s[c], off);
            s2[c] += __shfl_xor(s2[c], off);
        }
    }
    __shared__ double red[4][2 * DD];
    if (lane == 0) {
#pragma unroll
        for (int c = 0; c < DD; c++) { red[wid][c] = s[c]; red[wid][DD + c] = s2[c]; }
    }
    __syncthreads();
    if (tid < 2 * DD) {
        double t = red[0][tid] + red[1][tid] + red[2][tid] + red[3][tid];
        part[(size_t)blk * 2 * DD + tid] = t;
    }
}

__global__ __launch_bounds__(256) void k_stats_part_x(const float* __restrict__ x,
                                                      double* __restrict__ part) {
    const int i = blockIdx.x * 256 + threadIdx.x;
    float h[DD];
    const f4* xr = (const f4*)(x + (size_t)i * DD);
#pragma unroll
    for (int q = 0; q < 4; q++) {
        f4 v = xr[q];
        h[4*q+0] = v.x; h[4*q+1] = v.y; h[4*q+2] = v.z; h[4*q+3] = v.w;
    }
    colstat_reduce_store(h, part, blockIdx.x, threadIdx.x);
}

// ---------------- center (fused col-stat finalize): xc, packed fp16, sq, zero counters/tickets ----------------
__global__ __launch_bounds__(256) void k_center(const float* __restrict__ x,
                                                const double* __restrict__ part1,
                                                float* __restrict__ xc,
                                                uint32_t* __restrict__ xch,
                                                float* __restrict__ sqh,
                                                unsigned* __restrict__ gcnt,
                                                unsigned* __restrict__ fb_cnt,
                                                unsigned* __restrict__ ticket2,
                                                unsigned* __restrict__ ticket3,
                                                float* __restrict__ meanp,
                                                float* __restrict__ stdx) {
    __shared__ double red[32];
    __shared__ __align__(16) float msh[16];
    const int tid = threadIdx.x;
    if (tid < 32) {
        double t = 0.0;
        for (int b = 0; b < 32; b++) t += part1[(size_t)b * 32 + tid];
        red[tid] = t;
    }
    __syncthreads();
    if (tid < 16) {
        double s = red[tid], q = red[16 + tid];
        double mu = s / (double)NN;
        double var = (q - s * s / (double)NN) / (double)(NN - 1);
        float mf = (float)mu, sf = (float)sqrt(var > 0.0 ? var : 0.0);
        msh[tid] = mf;
        if (blockIdx.x == 0) { meanp[tid] = mf; stdx[tid] = sf; }
    }
    __syncthreads();

    const int i = blockIdx.x * 256 + tid;
    const f4* xr = (const f4*)(x + (size_t)i * DD);
    f4* xo = (f4*)(xc + (size_t)i * DD);
    uint32_t* xh = xch + (size_t)i * 8;
    float s = 0.f;
#pragma unroll
    for (int q = 0; q < 4; q++) {
        f4 m = *(const f4*)&msh[q * 4];
        f4 v = xr[q];
        v.x -= m.x; v.y -= m.y; v.z -= m.z; v.w -= m.w;
        xo[q] = v;
        _Float16 h0 = (_Float16)v.x, h1 = (_Float16)v.y, h2 = (_Float16)v.z, h3 = (_Float16)v.w;
        float r0 = (float)h0, r1 = (float)h1, r2 = (float)h2, r3 = (float)h3;
        s += r0 * r0 + r1 * r1 + r2 * r2 + r3 * r3;
        f16x2 p0 = {h0, h1}, p1 = {h2, h3};
        xh[q * 2 + 0] = __builtin_bit_cast(uint32_t, p0);
        xh[q * 2 + 1] = __builtin_bit_cast(uint32_t, p1);
    }
    sqh[i] = s;
    gcnt[i] = 0;
    if (i == 0) { fb_cnt[0] = 0; ticket2[0] = 0; ticket3[0] = 0; }
}

// ---------------- thresh: per (row, 256-col quarter) sorted top-15 d2 list ----------------
__global__ __launch_bounds__(256, 2) void k_thresh(const uint32_t* __restrict__ xch,
                                                   const float* __restrict__ sqh,
                                                   float* __restrict__ smlh) {
    __shared__ uint32_t tileA[16 * 128];  // frag-order, 8KB (256 rows)
    __shared__ float sqs[256];            // 1KB
    __shared__ float lists[4][64][15];    // 15KB
    const int tid = threadIdx.x, wid = tid >> 6, lane = tid & 63;
    const int r = lane & 15, h = lane >> 4;
    const int iG = blockIdx.x >> 2, qc = blockIdx.x & 3;
    const int jbase = qc << 8;
    const int i0 = (iG * 4 + wid) << 4;
    const int i = i0 + r;

    uint2 bu = *(const uint2*)(xch + (size_t)i * 8 + h * 2);
    f16x4 bf = __builtin_bit_cast(f16x4, bu);
    const float sqi = sqh[i];

    {
        int jl = tid;
        const uint4* src = (const uint4*)(xch + (size_t)(jbase + jl) * 8);
        uint4 a = src[0], b = src[1];
        uint32_t* base = tileA + ((jl >> 4) * 128 + (jl & 15) * 2);
        *(uint2*)(base)      = make_uint2(a.x, a.y);
        *(uint2*)(base + 32) = make_uint2(a.z, a.w);
        *(uint2*)(base + 64) = make_uint2(b.x, b.y);
        *(uint2*)(base + 96) = make_uint2(b.z, b.w);
        sqs[jl] = sqh[jbase + jl];
    }
    __syncthreads();

    unsigned lst[15];
#pragma unroll
    for (int c = 0; c < 15; c++) lst[c] = 0x7F7FFFFFu;
    unsigned T = 0x7F7FFFFFu, Tg = 0x7F7FFFFFu;

    for (int jt = 0; jt < 16; jt++) {
        uint2 au = *(const uint2*)(tileA + (jt * 128 + lane * 2));
        f16x4 af = __builtin_bit_cast(f16x4, au);
        f32x4 dot = __builtin_amdgcn_mfma_f32_16x16x16f16(af, bf, (f32x4){0.f, 0.f, 0.f, 0.f}, 0, 0, 0);
        f32x4 sq4 = *(const f32x4*)&sqs[jt * 16 + h * 4];
        bool fired = false;
#pragma unroll
        for (int q = 0; q < 4; q++) {
            float d2 = fmaf(-2.0f, dot[q], sqi + sq4[q]);
            float d2c = fmaxf(d2, 0.0f);
            unsigned u = __float_as_uint(d2c);
            if (u < Tg) {
                fired = true;
#pragma unroll
                for (int c = 0; c < 15; c++) {
                    unsigned lo = umn(lst[c], u), hi = umx(lst[c], u);
                    lst[c] = lo; u = hi;
                }
                T = lst[14];
            }
        }
        if (__any(fired)) {
            unsigned t1 = umn(T, (unsigned)__shfl_xor((int)T, 16));
            Tg = umn(t1, (unsigned)__shfl_xor((int)t1, 32));
        }
    }
#pragma unroll
    for (int c = 0; c < 15; c++) lists[wid][lane][c] = __uint_as_float(lst[c]);
    __syncthreads();
    if (h == 0) {
        int p0 = 0, p1 = 0, p2 = 0, p3 = 0;
        float* dst = smlh + ((size_t)i * 4 + qc) * 15;
        for (int rr = 0; rr < 15; rr++) {
            float v0 = (p0 < 15) ? lists[wid][r +  0][p0] : FLT_MAX;
            float v1 = (p1 < 15) ? lists[wid][r + 16][p1] : FLT_MAX;
            float v2 = (p2 < 15) ? lists[wid][r + 32][p2] : FLT_MAX;
            float v3 = (p3 < 15) ? lists[wid][r + 48][p3] : FLT_MAX;
            float m = fminf(fminf(v0, v1), fminf(v2, v3));
            if (v0 == m) p0++; else if (v1 == m) p1++; else if (v2 == m) p2++; else p3++;
            dst[rr] = m;
        }
    }
}

// ---------------- thrmerge (fused row-sum partials): thr[i] + per-block (S, SQ) partials ----------------
__global__ __launch_bounds__(256) void k_thrmerge(const float* __restrict__ smlh,
                                                  const uint32_t* __restrict__ xch,
                                                  const float* __restrict__ sqh,
                                                  float* __restrict__ thr,
                                                  double* __restrict__ rowpart) {
    const int tid = threadIdx.x, wid = tid >> 6, lane = tid & 63;
    const int i = blockIdx.x * 256 + tid;
    {
        const float* L0 = smlh + (size_t)i * 60;
        const float* L1 = L0 + 15;
        const float* L2 = L0 + 30;
        const float* L3 = L0 + 45;
        int p0 = 0, p1 = 0, p2 = 0, p3 = 0;
        float m = 0.f;
        for (int rr = 0; rr < 15; rr++) {
            float v0 = L0[p0], v1 = L1[p1], v2 = L2[p2], v3 = L3[p3];
            m = fminf(fminf(v0, v1), fminf(v2, v3));
            if (v0 == m) p0++; else if (v1 == m) p1++; else if (v2 == m) p2++; else p3++;
        }
        thr[i] = m;
    }
    double s[17];
    {
        const uint4* p = (const uint4*)(xch + (size_t)i * 8);
        uint4 a = p[0], b = p[1];
        uint32_t w[8] = {a.x, a.y, a.z, a.w, b.x, b.y, b.z, b.w};
#pragma unroll
        for (int c = 0; c < 8; c++) {
            f16x2 hh = __builtin_bit_cast(f16x2, w[c]);
            s[2 * c]     = (double)(float)hh[0];
            s[2 * c + 1] = (double)(float)hh[1];
        }
        s[16] = (double)sqh[i];
    }
#pragma unroll
    for (int c = 0; c < 17; c++) {
#pragma unroll
        for (int off = 1; off < 64; off <<= 1) s[c] += __shfl_xor(s[c], off);
    }
    __shared__ double red2[4][17];
    if (lane == 0) {
#pragma unroll
        for (int c = 0; c < 17; c++) red2[wid][c] = s[c];
    }
    __syncthreads();
    if (tid < 17) {
        rowpart[(size_t)blockIdx.x * 32 + tid] =
            red2[0][tid] + red2[1][tid] + red2[2][tid] + red2[3][tid];
    }
}

// ---------------- pass1 lean: s1 partials + LDS-buffered -> compact per-row candidates ----------------
__global__ __launch_bounds__(512, 8) void k_pass1_lean(const uint32_t* __restrict__ xch,
                                                       const float* __restrict__ sqh,
                                                       const float* __restrict__ thr,
                                                       float* __restrict__ s1p,
                                                       unsigned* __restrict__ gcnt,
                                                       float* __restrict__ candG) {
    __shared__ uint32_t tileA[8 * 512];       // 16KB frag-order
    __shared__ float sqs[512];                // 2KB
    __shared__ float clist[128][CAPC];        // 16KB candidate lists
    __shared__ unsigned ccnt[128];            // 512B
    const int tid = threadIdx.x, wid = tid >> 6, lane = tid & 63;
    const int r = lane & 15, h = lane >> 4;
    const int iG = blockIdx.x >> 4, chunk = blockIdx.x & 15;
    const int jbase = chunk << 9;
    const int i0 = (iG * 8 + wid) << 4;
    const int i = i0 + r;
    const int lrow = wid * 16 + r;

    uint2 bu = *(const uint2*)(xch + (size_t)i * 8 + h * 2);
    f16x4 bf = __builtin_bit_cast(f16x4, bu);
    const float sqi = sqh[i];
    const float Tf = thr[i];

    if (tid < 128) ccnt[tid] = 0;
    {
        int jl = tid;
        const uint4* src = (const uint4*)(xch + (size_t)(jbase + jl) * 8);
        uint4 a = src[0], b = src[1];
        uint32_t* base = tileA + ((jl >> 4) * 128 + (jl & 15) * 2);
        *(uint2*)(base)      = make_uint2(a.x, a.y);
        *(uint2*)(base + 32) = make_uint2(a.z, a.w);
        *(uint2*)(base + 64) = make_uint2(b.x, b.y);
        *(uint2*)(base + 96) = make_uint2(b.z, b.w);
        sqs[jl] = sqh[jbase + jl];
    }
    __syncthreads();

    float s1 = 0.f;
    for (int jt = 0; jt < 32; jt++) {
        uint2 au = *(const uint2*)(tileA + (jt * 128 + lane * 2));
        f16x4 af = __builtin_bit_cast(f16x4, au);
        f32x4 dot = __builtin_amdgcn_mfma_f32_16x16x16f16(af, bf, (f32x4){0.f, 0.f, 0.f, 0.f}, 0, 0, 0);
        f32x4 sq4 = *(const f32x4*)&sqs[jt * 16 + h * 4];
#pragma unroll
        for (int q = 0; q < 4; q++) {
            float d2 = fmaf(-2.0f, dot[q], sqi + sq4[q]);
            float d2c = fmaxf(d2, 0.0f);
            s1 += fsqrt(d2c);
            if (d2c <= Tf) {                       // rare; LDS atomic, no HBM traffic
                unsigned idx = atomicAdd(&ccnt[lrow], 1u);
                if (idx < CAPC) clist[lrow][idx] = d2c;
            }
        }
    }
    s1 += __shfl_xor(s1, 16); s1 += __shfl_xor(s1, 32);
    if (h == 0) s1p[(size_t)chunk * NN + i] = s1;
    __syncthreads();
    if (tid < 128) {
        const int gi = iG * 128 + tid;
        const unsigned c = ccnt[tid];
        const unsigned cw = umn(c, (unsigned)CAPC);
        const unsigned addv = (c <= (unsigned)CAPC) ? c : (c + 0x10000u);
        unsigned base = atomicAdd(&gcnt[gi], addv) & 0xFFFFu;
        float* dst = candG + (size_t)gi * CAPR;
        for (unsigned s = 0; s < cw; s++) {
            unsigned p = base + s;
            if (p < (unsigned)CAPR) dst[p] = clist[tid][s];
        }
    }
}

// ---------------- density (+ fused adaptk via last-block ticket) ----------------
__global__ __launch_bounds__(256) void k_merge_den(const float* __restrict__ s1p,
                                                   const double* __restrict__ rowpart,
                                                   const uint32_t* __restrict__ xch,
                                                   const float* __restrict__ sqh,
                                                   float* __restrict__ den,
                                                   unsigned* __restrict__ ticket2,
                                                   int* __restrict__ kptr) {
    __shared__ double Ssh[17];
    __shared__ unsigned rank_sh;
    const int tid = threadIdx.x, wid = tid >> 6, lane = tid & 63;
    if (tid < 17) {
        double t = 0.0;
        for (int b = 0; b < 32; b++) t += rowpart[(size_t)b * 32 + tid];
        Ssh[tid] = t;
    }
    __syncthreads();
    const int i = blockIdx.x * 256 + tid;
    double g1 = 0.0;
#pragma unroll
    for (int c = 0; c < CH2; c++) g1 += (double)s1p[(size_t)c * NN + i];
    double dotS = 0.0;
    {
        const uint4* p = (const uint4*)(xch + (size_t)i * 8);
        uint4 a = p[0], b = p[1];
        uint32_t w[8] = {a.x, a.y, a.z, a.w, b.x, b.y, b.z, b.w};
#pragma unroll
        for (int c = 0; c < 8; c++) {
            f16x2 hh = __builtin_bit_cast(f16x2, w[c]);
            dotS += (double)(float)hh[0] * Ssh[2 * c];
            dotS += (double)(float)hh[1] * Ssh[2 * c + 1];
        }
    }
    double s2 = (double)NN * (double)sqh[i] + Ssh[16] - 2.0 * dotS;
    double var = (s2 - g1 * g1 / (double)NN) / (double)(NN - 1);
    den[i] = (float)sqrt(var > 0.0 ? var : 0.0);
    // last-block adaptk (device-scope fence pair per G16)
    __threadfence();
    if (tid == 0) rank_sh = atomicAdd(ticket2, 1u);
    __syncthreads();
    if (rank_sh == 31) {
        __threadfence();
        __shared__ float redf[4];
        __shared__ int redi[4];
        __shared__ float dmax_sh;
        float mx = 0.f;
        for (int r2 = tid; r2 < NN; r2 += 256) mx = fmaxf(mx, den[r2]);
#pragma unroll
        for (int off = 1; off < 64; off <<= 1) mx = fmaxf(mx, __shfl_xor(mx, off));
        if (lane == 0) redf[wid] = mx;
        __syncthreads();
        if (tid == 0)
            dmax_sh = fmaxf(fmaxf(redf[0], redf[1]), fmaxf(redf[2], redf[3]));
        __syncthreads();
        const float dmax = dmax_sh + EPSF;
        int ks = 0;
        for (int r2 = tid; r2 < NN; r2 += 256) {
            float f = den[r2] / dmax;
            float kf = fminf(fmaxf(5.0f + 10.0f * f, 5.0f), 20.0f);
            ks += (int)kf;
        }
#pragma unroll
        for (int off = 1; off < 64; off <<= 1) ks += __shfl_xor(ks, off);
        if (lane == 0) redi[wid] = ks;
        __syncthreads();
        if (tid == 0) {
            int t = redi[0] + redi[1] + redi[2] + redi[3];
            kptr[0] = (int)((float)t / (float)NN);
        }
    }
}

// ---------------- sigma: k-th smallest d2 per row from compact candidates ----------------
__global__ __launch_bounds__(512) void k_sigma(const unsigned* __restrict__ gcnt,
                                               const float* __restrict__ candG,
                                               const int* __restrict__ kptr,
                                               float* __restrict__ sig2,
                                               unsigned* __restrict__ fb_cnt,
                                               unsigned* __restrict__ fb_list) {
    const int tid = threadIdx.x, wid = tid >> 6, lane = tid & 63;
    const int i = blockIdx.x * 8 + wid;
    const int k = kptr[0];
    const unsigned n = gcnt[i];
    if (n <= (unsigned)CAPR) {
        const float* src = candG + (size_t)i * CAPR;
        float v[6];
#pragma unroll
        for (int c = 0; c < 6; c++)
            v[c] = (lane + 64 * c < (int)n) ? src[lane + 64 * c] : FLT_MAX;
        float wm = 0.f;
        for (int rr = 0; rr < k; rr++) {
            float m = v[0];
#pragma unroll
            for (int c = 1; c < 6; c++) m = fminf(m, v[c]);
            wm = m;
#pragma unroll
            for (int off = 1; off < 64; off <<= 1) wm = fminf(wm, __shfl_xor(wm, off));
            unsigned long long b = __ballot(m == wm);
            if (lane == (int)(__ffsll(b) - 1)) {
                bool done = false;
#pragma unroll
                for (int c = 0; c < 6; c++) {
                    bool hit = !done && (v[c] == wm);
                    v[c] = hit ? FLT_MAX : v[c];
                    done = done || hit;
                }
            }
        }
        if (lane == 0) sig2[i] = wm;
    } else {
        if (lane == 0) {
            unsigned slot = atomicAdd(fb_cnt, 1u);
            fb_list[slot] = (unsigned)i;
        }
    }
}

// ---------------- sigma fallback: exact k-th smallest via block-parallel radix-select ----------------
__global__ __launch_bounds__(512) void k_sigma_fb(const unsigned* __restrict__ fb_cnt,
                                                  const unsigned* __restrict__ fb_list,
                                                  const uint32_t* __restrict__ xch,
                                                  const float* __restrict__ sqh,
                                                  const int* __restrict__ kptr,
                                                  float* __restrict__ sig2) {
    __shared__ unsigned redc[8];
    const int tid = threadIdx.x, wid = tid >> 6, lane = tid & 63;
    const unsigned nfb = fb_cnt[0];
    const int k = kptr[0];
    for (unsigned e = blockIdx.x; e < nfb; e += gridDim.x) {
        const int i = (int)fb_list[e];
        uint32_t xi[8];
        {
            const uint4* p = (const uint4*)(xch + (size_t)i * 8);
            uint4 a = p[0], b = p[1];
            xi[0] = a.x; xi[1] = a.y; xi[2] = a.z; xi[3] = a.w;
            xi[4] = b.x; xi[5] = b.y; xi[6] = b.z; xi[7] = b.w;
        }
        const float sqi = sqh[i];
        unsigned vb[16];
#pragma unroll
        for (int s = 0; s < 16; s++) {
            int j = tid + (s << 9);
            const uint4* q = (const uint4*)(xch + (size_t)j * 8);
            uint4 c0 = q[0], c1 = q[1];
            uint32_t xj[8] = {c0.x, c0.y, c0.z, c0.w, c1.x, c1.y, c1.z, c1.w};
            float dot = 0.f;
#pragma unroll
            for (int c = 0; c < 8; c++) dot = fdot2a(xi[c], xj[c], dot);
            float d2c = fmaxf(fmaf(-2.0f, dot, sqi + sqh[j]), 0.0f);
            vb[s] = __float_as_uint(d2c);
        }
        unsigned prefix = 0;
        for (int bit = 30; bit >= 0; bit--) {
            unsigned trial = prefix | (1u << bit);
            unsigned cnt = 0;
#pragma unroll
            for (int s = 0; s < 16; s++) cnt += (vb[s] < trial) ? 1u : 0u;
#pragma unroll
            for (int off = 1; off < 64; off <<= 1) cnt += (unsigned)__shfl_xor((int)cnt, off);
            if (lane == 0) redc[wid] = cnt;
            __syncthreads();
            unsigned tot = redc[0] + redc[1] + redc[2] + redc[3]
                         + redc[4] + redc[5] + redc[6] + redc[7];
            if (tot < (unsigned)k) prefix = trial;
            __syncthreads();
        }
        if (tid == 0) sig2[i] = __uint_as_float(prefix);
        __syncthreads();
    }
}

// ---------------- drift (MFMA QK + MFMA PV): partial numerator/wsum, [chunk][i] layout ----------------
__global__ __launch_bounds__(512, 8) void k_drift_mfma(const uint32_t* __restrict__ xch,
                                                       const float* __restrict__ sqh,
                                                       const float* __restrict__ sig2,
                                                       float* __restrict__ nump,
                                                       float* __restrict__ wsp) {
    __shared__ uint32_t tileA[8 * 512];    // frag-order, 16KB
    __shared__ uint32_t tileT[16 * 256];   // transposed [d][jpair] +2d rotated, 16KB
    __shared__ float sqs[512];             // 2KB
    const int tid = threadIdx.x, wid = tid >> 6, lane = tid & 63;
    const int r = lane & 15, h = lane >> 4;
    const int iG = blockIdx.x >> 4, chunk = blockIdx.x & 15;
    const int jb = chunk << 9;
    const int i0 = (iG * 8 + wid) << 4;
    const int i = i0 + r;

    const float sg = sig2[i];
    const float nl2 = -1.4426950408889634f / (2.0f * sg + EPSF);
    uint2 bu = *(const uint2*)(xch + (size_t)i * 8 + h * 2);
    f16x4 bf = __builtin_bit_cast(f16x4, bu);
    const float sqi = sqh[i];

    f32x4 acc = {0.f, 0.f, 0.f, 0.f};
    float ws = 0.f;

    {
        int jl = tid;
        const uint4* src = (const uint4*)(xch + (size_t)(jb + jl) * 8);
        uint4 a = src[0], b = src[1];
        uint32_t* base = tileA + ((jl >> 4) * 128 + (jl & 15) * 2);
        *(uint2*)(base)      = make_uint2(a.x, a.y);
        *(uint2*)(base + 32) = make_uint2(a.z, a.w);
        *(uint2*)(base + 64) = make_uint2(b.x, b.y);
        *(uint2*)(base + 96) = make_uint2(b.z, b.w);
        sqs[jl] = sqh[jb + jl];
        if (tid < 256) {
            int jp = tid;
            const uint4* sA = (const uint4*)(xch + (size_t)(jb + 2 * jp) * 8);
            const uint4* sB = (const uint4*)(xch + (size_t)(jb + 2 * jp + 1) * 8);
            uint4 a0 = sA[0], a1 = sA[1], b0 = sB[0], b1 = sB[1];
            uint32_t rA[8] = {a0.x, a0.y, a0.z, a0.w, a1.x, a1.y, a1.z, a1.w};
            uint32_t rB[8] = {b0.x, b0.y, b0.z, b0.w, b1.x, b1.y, b1.z, b1.w};
#pragma unroll
            for (int d = 0; d < 16; d++) {
                uint32_t lo = (d & 1) ? (rA[d >> 1] >> 16) : (rA[d >> 1] & 0xFFFFu);
                uint32_t hi = (d & 1) ? (rB[d >> 1] & 0xFFFF0000u) : (rB[d >> 1] << 16);
                tileT[d * 256 + ((jp + 2 * d) & 255)] = lo | hi;
            }
        }
    }
    __syncthreads();
    for (int jt = 0; jt < 32; jt++) {
        uint2 au = *(const uint2*)(tileA + (jt * 128 + lane * 2));
        f16x4 af = __builtin_bit_cast(f16x4, au);
        f32x4 dot = __builtin_amdgcn_mfma_f32_16x16x16f16(af, bf, (f32x4){0.f, 0.f, 0.f, 0.f}, 0, 0, 0);
        f32x4 sq4 = *(const f32x4*)&sqs[jt * 16 + h * 4];
        float w0, w1, w2, w3;
        {
            float d2, d;
            d2 = fmaf(-2.f, dot[0], sqi + sq4[0]); d = fsqrt(fmaxf(d2, 0.f)); w0 = fexp2(d * nl2);
            d2 = fmaf(-2.f, dot[1], sqi + sq4[1]); d = fsqrt(fmaxf(d2, 0.f)); w1 = fexp2(d * nl2);
            d2 = fmaf(-2.f, dot[2], sqi + sq4[2]); d = fsqrt(fmaxf(d2, 0.f)); w2 = fexp2(d * nl2);
            d2 = fmaf(-2.f, dot[3], sqi + sq4[3]); d = fsqrt(fmaxf(d2, 0.f)); w3 = fexp2(d * nl2);
        }
        ws += (w0 + w1) + (w2 + w3);
        uint2 wp = make_uint2(pkrtz(w0, w1), pkrtz(w2, w3));
        f16x4 wf = __builtin_bit_cast(f16x4, wp);
        int jp0 = jt * 8 + h * 2;
        uint2 tv = *(const uint2*)(tileT + (r * 256 + ((jp0 + 2 * r) & 255)));
        f16x4 btf = __builtin_bit_cast(f16x4, tv);
        acc = __builtin_amdgcn_mfma_f32_16x16x16f16(wf, btf, acc, 0, 0, 0);
    }
    ws += __shfl_xor(ws, 16); ws += __shfl_xor(ws, 32);
    if (h == 0) wsp[(size_t)chunk * NN + i] = ws;
#pragma unroll
    for (int q = 0; q < 4; q++) {
        int irow = i0 + h * 4 + q;
        nump[((size_t)chunk * NN + irow) * 16 + r] = acc[q];
    }
}

// ---------------- fused: drift merge + h-update + col-stats + (all-block barrier) + final scale ----------------
__global__ __launch_bounds__(256) void k_hpre_final(const float* __restrict__ xc,
                                                    const float* __restrict__ nump,
                                                    const float* __restrict__ wsp,
                                                    const float* __restrict__ noise,
                                                    const float* __restrict__ alpha,
                                                    const float* __restrict__ stdx,
                                                    const float* __restrict__ meanp,
                                                    float* __restrict__ out,
                                                    double* __restrict__ part,
                                                    unsigned* __restrict__ ticket3) {
    const int tid = threadIdx.x;
    const int i = blockIdx.x * 256 + tid;
    const float step = powf(16.0f, -alpha[0]);
    float w = 0.f;
#pragma unroll
    for (int c = 0; c < CH2; c++) w += wsp[(size_t)c * NN + i];   // coalesced
    const float inv = 1.0f / (w + EPSF);
    f4 dr[4] = {{0,0,0,0},{0,0,0,0},{0,0,0,0},{0,0,0,0}};
#pragma unroll
    for (int c = 0; c < CH2; c++) {
        const f4* np = (const f4*)(nump + ((size_t)c * NN + i) * 16);  // 64B/lane contiguous
#pragma unroll
        for (int q = 0; q < 4; q++) {
            f4 v = np[q];
            dr[q].x += v.x; dr[q].y += v.y; dr[q].z += v.z; dr[q].w += v.w;
        }
    }
    const f4* xr = (const f4*)(xc + (size_t)i * DD);
    const f4* nr = (const f4*)(noise + (size_t)i * DD);
    float h[DD];
#pragma unroll
    for (int q = 0; q < 4; q++) {
        f4 a = xr[q], n = nr[q];
        h[4*q+0] = a.x + step * (dr[q].x * inv - a.x) + n.x * 0.01f;
        h[4*q+1] = a.y + step * (dr[q].y * inv - a.y) + n.y * 0.01f;
        h[4*q+2] = a.z + step * (dr[q].z * inv - a.z) + n.z * 0.01f;
        h[4*q+3] = a.w + step * (dr[q].w * inv - a.w) + n.w * 0.01f;
    }
    colstat_reduce_store(h, part, blockIdx.x, tid);
    // all-block barrier: 32 blocks, trivially co-resident; release = fence+ticket, acquire = spin+fence
    __threadfence();
    __syncthreads();
    if (tid == 0) {
        atomicAdd(ticket3, 1u);
        while (atomicAdd(ticket3, 0u) < 32u) __builtin_amdgcn_s_sleep(8);
    }
    __syncthreads();
    __threadfence();
    // phase B: global column std of h -> ratio; out = h*ratio + mean (h still in registers)
    __shared__ __align__(16) float rsh[16];
    __shared__ __align__(16) float msh2[16];
    if (tid < 16) {
        double s = 0.0, q = 0.0;
        for (int b = 0; b < 32; b++) {
            s += part[(size_t)b * 32 + tid];
            q += part[(size_t)b * 32 + 16 + tid];
        }
        double var = (q - s * s / (double)NN) / (double)(NN - 1);
        float stdh = (float)sqrt(var > 0.0 ? var : 0.0);
        rsh[tid] = stdx[tid] / (stdh + EPSF);
        msh2[tid] = meanp[tid];
    }
    __syncthreads();
    f4* ho = (f4*)(out + (size_t)i * DD);
#pragma unroll
    for (int q = 0; q < 4; q++) {
        f4 rv = *(const f4*)&rsh[q * 4];
        f4 mv = *(const f4*)&msh2[q * 4];
        f4 o;
        o.x = h[4*q+0] * rv.x + mv.x;
        o.y = h[4*q+1] * rv.y + mv.y;
        o.z = h[4*q+2] * rv.z + mv.z;
        o.w = h[4*q+3] * rv.w + mv.w;
        ho[q] = o;
    }
}

extern "C" void kernel_launch(void* const* d_in, const int* in_sizes, int n_in,
                              void* d_out, int out_size, void* d_ws, size_t ws_size,
                              hipStream_t stream) {
    (void)in_sizes; (void)n_in; (void)out_size; (void)ws_size;
    const float* x = (const float*)d_in[0];
    const float* noise = (const float*)d_in[1];
    const float* alpha = (const float*)d_in[2];
    float* out = (float*)d_out;

    double* part1 = (double*)d_ws;                        // 32*32 dbl
    double* part2 = part1 + 1024;                         // 32*32 dbl
    double* rowpart = part2 + 1024;                       // 32*32 dbl
    float*    xc   = (float*)(rowpart + 1024);            // N*16
    uint32_t* xch  = (uint32_t*)(xc + (size_t)NN * DD);   // N*8
    float*    sqh  = (float*)(xch + (size_t)NN * 8);      // N
    float*    den  = sqh + NN;                            // N
    float*    smlh = den + NN;                            // N*4*15
    float*    thr  = smlh + (size_t)NN * 60;              // N
    float*    s1p  = thr + NN;                            // 16*N
    unsigned* gcnt = (unsigned*)(s1p + (size_t)NN * CH2); // N
    unsigned* fb_cnt = gcnt + NN;                         // 1
    unsigned* ticket2 = fb_cnt + 1;                       // 1
    unsigned* ticket3 = fb_cnt + 2;                       // 1 (pad to 64)
    unsigned* fb_list = fb_cnt + 64;                      // N
    float*    candG = (float*)(fb_list + NN);             // N*384 (12.6MB)
    float*    sig2 = candG + (size_t)NN * CAPR;           // N
    float*    nump = sig2 + NN;                           // 16*N*16 (8.4MB)
    float*    wsp  = nump + (size_t)NN * CH2 * 16;        // 16*N
    float*    meanp = wsp + (size_t)NN * CH2;             // 16
    float*    stdx  = meanp + DD;                         // 16
    int*      kptr  = (int*)(stdx + DD);                  // 1

    k_stats_part_x<<<32, 256, 0, stream>>>(x, part1);
    k_center<<<32, 256, 0, stream>>>(x, part1, xc, xch, sqh, gcnt, fb_cnt, ticket2, ticket3, meanp, stdx);
    k_thresh<<<512, 256, 0, stream>>>(xch, sqh, smlh);
    k_thrmerge<<<32, 256, 0, stream>>>(smlh, xch, sqh, thr, rowpart);
    k_pass1_lean<<<1024, 512, 0, stream>>>(xch, sqh, thr, s1p, gcnt, candG);
    k_merge_den<<<32, 256, 0, stream>>>(s1p, rowpart, xch, sqh, den, ticket2, kptr);
    k_sigma<<<1024, 512, 0, stream>>>(gcnt, candG, kptr, sig2, fb_cnt, fb_list);
    k_sigma_fb<<<128, 512, 0, stream>>>(fb_cnt, fb_list, xch, sqh, kptr, sig2);
    k_drift_mfma<<<1024, 512, 0, stream>>>(xch, sqh, sig2, nump, wsp);
    k_hpre_final<<<32, 256, 0, stream>>>(xc, nump, wsp, noise, alpha, stdx, meanp, out, part2, ticket3);
}

// Round 15
// 139.348 us; speedup vs baseline: 1.0766x; 1.0766x over previous
//
#include <hip/hip_runtime.h>
#include <hip/hip_fp16.h>
#include <cfloat>
#include <cmath>
#include <cstdint>

#define NN 8192
#define DD 16
#define EPSF 1e-8f
#define CH2 16          // j-chunks of 512 (lean/drift)
#define CAPC 32         // LDS candidate slots per (row, chunk)
#define CAPR 384        // compact global candidate slots per row

typedef float4 f4;
typedef _Float16 f16x4 __attribute__((ext_vector_type(4)));
typedef _Float16 f16x2 __attribute__((ext_vector_type(2)));
typedef float f32x4 __attribute__((ext_vector_type(4)));

__device__ __forceinline__ unsigned umn(unsigned a, unsigned b) { return a < b ? a : b; }
__device__ __forceinline__ unsigned umx(unsigned a, unsigned b) { return a < b ? b : a; }

__device__ __forceinline__ uint32_t pkrtz(float a, float b) {
    return __builtin_bit_cast(uint32_t, __builtin_amdgcn_cvt_pkrtz(a, b));
}

__device__ __forceinline__ float fsqrt(float x) {
#if defined(__has_builtin) && __has_builtin(__builtin_amdgcn_sqrtf)
    return __builtin_amdgcn_sqrtf(x);
#else
    return sqrtf(x);
#endif
}

__device__ __forceinline__ float fexp2(float x) {
#if defined(__has_builtin) && __has_builtin(__builtin_amdgcn_exp2f)
    return __builtin_amdgcn_exp2f(x);
#else
    return exp2f(x);
#endif
}

__device__ __forceinline__ float fdot2a(uint32_t a, uint32_t b, float c) {
#if defined(__has_builtin) && __has_builtin(__builtin_amdgcn_fdot2)
    return __builtin_amdgcn_fdot2(__builtin_bit_cast(f16x2, a), __builtin_bit_cast(f16x2, b), c, false);
#else
    __half2 ah = __builtin_bit_cast(__half2, a), bh = __builtin_bit_cast(__half2, b);
    float2 af = __half22float2(ah), bf = __half22float2(bh);
    return fmaf(af.x, bf.x, fmaf(af.y, bf.y, c));
#endif
}

// ---------------- column-stat partials ----------------
__device__ __forceinline__ void colstat_reduce_store(const float h[DD], double* __restrict__ part,
                                                     int blk, int tid) {
    const int lane = tid & 63, wid = tid >> 6;
    double s[DD], s2[DD];
#pragma unroll
    for (int c = 0; c < DD; c++) { double a = (double)h[c]; s[c] = a; s2[c] = a * a; }
#pragma unroll
    for (int c = 0; c < DD; c++) {
#pragma unroll
        for (int off = 1; off < 64; off <<= 1) {
            s[c] += __shfl_xor(s[c], off);
            s2[c] += __shfl_xor(s2[c], off);
        }
    }
    __shared__ double red[4][2 * DD];
    if (lane == 0) {
#pragma unroll
        for (int c = 0; c < DD; c++) { red[wid][c] = s[c]; red[wid][DD + c] = s2[c]; }
    }
    __syncthreads();
    if (tid < 2 * DD) {
        double t = red[0][tid] + red[1][tid] + red[2][tid] + red[3][tid];
        part[(size_t)blk * 2 * DD + tid] = t;
    }
}

__global__ __launch_bounds__(256) void k_stats_part_x(const float* __restrict__ x,
                                                      double* __restrict__ part) {
    const int i = blockIdx.x * 256 + threadIdx.x;
    float h[DD];
    const f4* xr = (const f4*)(x + (size_t)i * DD);
#pragma unroll
    for (int q = 0; q < 4; q++) {
        f4 v = xr[q];
        h[4*q+0] = v.x; h[4*q+1] = v.y; h[4*q+2] = v.z; h[4*q+3] = v.w;
    }
    colstat_reduce_store(h, part, blockIdx.x, threadIdx.x);
}

// ---------------- center (fused col-stat finalize): xc, packed fp16, sq, zero counters ----------------
__global__ __launch_bounds__(256) void k_center(const float* __restrict__ x,
                                                const double* __restrict__ part1,
                                                float* __restrict__ xc,
                                                uint32_t* __restrict__ xch,
                                                float* __restrict__ sqh,
                                                unsigned* __restrict__ gcnt,
                                                unsigned* __restrict__ fb_cnt,
                                                float* __restrict__ meanp,
                                                float* __restrict__ stdx) {
    __shared__ double red[32];
    __shared__ __align__(16) float msh[16];
    const int tid = threadIdx.x;
    if (tid < 32) {
        double t = 0.0;
        for (int b = 0; b < 32; b++) t += part1[(size_t)b * 32 + tid];
        red[tid] = t;
    }
    __syncthreads();
    if (tid < 16) {
        double s = red[tid], q = red[16 + tid];
        double mu = s / (double)NN;
        double var = (q - s * s / (double)NN) / (double)(NN - 1);
        float mf = (float)mu, sf = (float)sqrt(var > 0.0 ? var : 0.0);
        msh[tid] = mf;
        if (blockIdx.x == 0) { meanp[tid] = mf; stdx[tid] = sf; }
    }
    __syncthreads();

    const int i = blockIdx.x * 256 + tid;
    const f4* xr = (const f4*)(x + (size_t)i * DD);
    f4* xo = (f4*)(xc + (size_t)i * DD);
    uint32_t* xh = xch + (size_t)i * 8;
    float s = 0.f;
#pragma unroll
    for (int q = 0; q < 4; q++) {
        f4 m = *(const f4*)&msh[q * 4];
        f4 v = xr[q];
        v.x -= m.x; v.y -= m.y; v.z -= m.z; v.w -= m.w;
        xo[q] = v;
        _Float16 h0 = (_Float16)v.x, h1 = (_Float16)v.y, h2 = (_Float16)v.z, h3 = (_Float16)v.w;
        float r0 = (float)h0, r1 = (float)h1, r2 = (float)h2, r3 = (float)h3;
        s += r0 * r0 + r1 * r1 + r2 * r2 + r3 * r3;
        f16x2 p0 = {h0, h1}, p1 = {h2, h3};
        xh[q * 2 + 0] = __builtin_bit_cast(uint32_t, p0);
        xh[q * 2 + 1] = __builtin_bit_cast(uint32_t, p1);
    }
    sqh[i] = s;
    gcnt[i] = 0;
    if (i == 0) fb_cnt[0] = 0;
}

// ---------------- thresh: per (row, 256-col quarter) sorted top-15 d2 list ----------------
__global__ __launch_bounds__(256, 2) void k_thresh(const uint32_t* __restrict__ xch,
                                                   const float* __restrict__ sqh,
                                                   float* __restrict__ smlh) {
    __shared__ uint32_t tileA[16 * 128];  // frag-order, 8KB (256 rows)
    __shared__ float sqs[256];            // 1KB
    __shared__ float lists[4][64][15];    // 15KB
    const int tid = threadIdx.x, wid = tid >> 6, lane = tid & 63;
    const int r = lane & 15, h = lane >> 4;
    const int iG = blockIdx.x >> 2, qc = blockIdx.x & 3;
    const int jbase = qc << 8;
    const int i0 = (iG * 4 + wid) << 4;
    const int i = i0 + r;

    uint2 bu = *(const uint2*)(xch + (size_t)i * 8 + h * 2);
    f16x4 bf = __builtin_bit_cast(f16x4, bu);
    const float sqi = sqh[i];

    {
        int jl = tid;
        const uint4* src = (const uint4*)(xch + (size_t)(jbase + jl) * 8);
        uint4 a = src[0], b = src[1];
        uint32_t* base = tileA + ((jl >> 4) * 128 + (jl & 15) * 2);
        *(uint2*)(base)      = make_uint2(a.x, a.y);
        *(uint2*)(base + 32) = make_uint2(a.z, a.w);
        *(uint2*)(base + 64) = make_uint2(b.x, b.y);
        *(uint2*)(base + 96) = make_uint2(b.z, b.w);
        sqs[jl] = sqh[jbase + jl];
    }
    __syncthreads();

    unsigned lst[15];
#pragma unroll
    for (int c = 0; c < 15; c++) lst[c] = 0x7F7FFFFFu;
    unsigned T = 0x7F7FFFFFu, Tg = 0x7F7FFFFFu;

    for (int jt = 0; jt < 16; jt++) {
        uint2 au = *(const uint2*)(tileA + (jt * 128 + lane * 2));
        f16x4 af = __builtin_bit_cast(f16x4, au);
        f32x4 dot = __builtin_amdgcn_mfma_f32_16x16x16f16(af, bf, (f32x4){0.f, 0.f, 0.f, 0.f}, 0, 0, 0);
        f32x4 sq4 = *(const f32x4*)&sqs[jt * 16 + h * 4];
        bool fired = false;
#pragma unroll
        for (int q = 0; q < 4; q++) {
            float d2 = fmaf(-2.0f, dot[q], sqi + sq4[q]);
            float d2c = fmaxf(d2, 0.0f);
            unsigned u = __float_as_uint(d2c);
            if (u < Tg) {
                fired = true;
#pragma unroll
                for (int c = 0; c < 15; c++) {
                    unsigned lo = umn(lst[c], u), hi = umx(lst[c], u);
                    lst[c] = lo; u = hi;
                }
                T = lst[14];
            }
        }
        if (__any(fired)) {
            unsigned t1 = umn(T, (unsigned)__shfl_xor((int)T, 16));
            Tg = umn(t1, (unsigned)__shfl_xor((int)t1, 32));
        }
    }
#pragma unroll
    for (int c = 0; c < 15; c++) lists[wid][lane][c] = __uint_as_float(lst[c]);
    __syncthreads();
    if (h == 0) {
        int p0 = 0, p1 = 0, p2 = 0, p3 = 0;
        float* dst = smlh + ((size_t)i * 4 + qc) * 15;
        for (int rr = 0; rr < 15; rr++) {
            float v0 = (p0 < 15) ? lists[wid][r +  0][p0] : FLT_MAX;
            float v1 = (p1 < 15) ? lists[wid][r + 16][p1] : FLT_MAX;
            float v2 = (p2 < 15) ? lists[wid][r + 32][p2] : FLT_MAX;
            float v3 = (p3 < 15) ? lists[wid][r + 48][p3] : FLT_MAX;
            float m = fminf(fminf(v0, v1), fminf(v2, v3));
            if (v0 == m) p0++; else if (v1 == m) p1++; else if (v2 == m) p2++; else p3++;
            dst[rr] = m;
        }
    }
}

// ---------------- thrmerge (fused row-sum partials): thr[i] + per-block (S, SQ) partials ----------------
__global__ __launch_bounds__(256) void k_thrmerge(const float* __restrict__ smlh,
                                                  const uint32_t* __restrict__ xch,
                                                  const float* __restrict__ sqh,
                                                  float* __restrict__ thr,
                                                  double* __restrict__ rowpart) {
    const int tid = threadIdx.x, wid = tid >> 6, lane = tid & 63;
    const int i = blockIdx.x * 256 + tid;
    {
        const float* L0 = smlh + (size_t)i * 60;
        const float* L1 = L0 + 15;
        const float* L2 = L0 + 30;
        const float* L3 = L0 + 45;
        int p0 = 0, p1 = 0, p2 = 0, p3 = 0;
        float m = 0.f;
        for (int rr = 0; rr < 15; rr++) {
            float v0 = L0[p0], v1 = L1[p1], v2 = L2[p2], v3 = L3[p3];
            m = fminf(fminf(v0, v1), fminf(v2, v3));
            if (v0 == m) p0++; else if (v1 == m) p1++; else if (v2 == m) p2++; else p3++;
        }
        thr[i] = m;
    }
    // row-sum partials: S[0..15] = sum of rounded xc, S[16] = sum of sq
    double s[17];
    {
        const uint4* p = (const uint4*)(xch + (size_t)i * 8);
        uint4 a = p[0], b = p[1];
        uint32_t w[8] = {a.x, a.y, a.z, a.w, b.x, b.y, b.z, b.w};
#pragma unroll
        for (int c = 0; c < 8; c++) {
            f16x2 hh = __builtin_bit_cast(f16x2, w[c]);
            s[2 * c]     = (double)(float)hh[0];
            s[2 * c + 1] = (double)(float)hh[1];
        }
        s[16] = (double)sqh[i];
    }
#pragma unroll
    for (int c = 0; c < 17; c++) {
#pragma unroll
        for (int off = 1; off < 64; off <<= 1) s[c] += __shfl_xor(s[c], off);
    }
    __shared__ double red2[4][17];
    if (lane == 0) {
#pragma unroll
        for (int c = 0; c < 17; c++) red2[wid][c] = s[c];
    }
    __syncthreads();
    if (tid < 17) {
        rowpart[(size_t)blockIdx.x * 32 + tid] =
            red2[0][tid] + red2[1][tid] + red2[2][tid] + red2[3][tid];
    }
}

// ---------------- pass1 lean: s1 partials + LDS-buffered -> compact per-row candidates ----------------
__global__ __launch_bounds__(512, 8) void k_pass1_lean(const uint32_t* __restrict__ xch,
                                                       const float* __restrict__ sqh,
                                                       const float* __restrict__ thr,
                                                       float* __restrict__ s1p,
                                                       unsigned* __restrict__ gcnt,
                                                       float* __restrict__ candG) {
    __shared__ uint32_t tileA[8 * 512];       // 16KB frag-order
    __shared__ float sqs[512];                // 2KB
    __shared__ float clist[128][CAPC];        // 16KB candidate lists
    __shared__ unsigned ccnt[128];            // 512B
    const int tid = threadIdx.x, wid = tid >> 6, lane = tid & 63;
    const int r = lane & 15, h = lane >> 4;
    const int iG = blockIdx.x >> 4, chunk = blockIdx.x & 15;
    const int jbase = chunk << 9;
    const int i0 = (iG * 8 + wid) << 4;
    const int i = i0 + r;
    const int lrow = wid * 16 + r;

    uint2 bu = *(const uint2*)(xch + (size_t)i * 8 + h * 2);
    f16x4 bf = __builtin_bit_cast(f16x4, bu);
    const float sqi = sqh[i];
    const float Tf = thr[i];

    if (tid < 128) ccnt[tid] = 0;
    {
        int jl = tid;
        const uint4* src = (const uint4*)(xch + (size_t)(jbase + jl) * 8);
        uint4 a = src[0], b = src[1];
        uint32_t* base = tileA + ((jl >> 4) * 128 + (jl & 15) * 2);
        *(uint2*)(base)      = make_uint2(a.x, a.y);
        *(uint2*)(base + 32) = make_uint2(a.z, a.w);
        *(uint2*)(base + 64) = make_uint2(b.x, b.y);
        *(uint2*)(base + 96) = make_uint2(b.z, b.w);
        sqs[jl] = sqh[jbase + jl];
    }
    __syncthreads();

    float s1 = 0.f;
    for (int jt = 0; jt < 32; jt++) {
        uint2 au = *(const uint2*)(tileA + (jt * 128 + lane * 2));
        f16x4 af = __builtin_bit_cast(f16x4, au);
        f32x4 dot = __builtin_amdgcn_mfma_f32_16x16x16f16(af, bf, (f32x4){0.f, 0.f, 0.f, 0.f}, 0, 0, 0);
        f32x4 sq4 = *(const f32x4*)&sqs[jt * 16 + h * 4];
#pragma unroll
        for (int q = 0; q < 4; q++) {
            float d2 = fmaf(-2.0f, dot[q], sqi + sq4[q]);
            float d2c = fmaxf(d2, 0.0f);
            s1 += fsqrt(d2c);
            if (d2c <= Tf) {                       // rare; LDS atomic, no HBM traffic
                unsigned idx = atomicAdd(&ccnt[lrow], 1u);
                if (idx < CAPC) clist[lrow][idx] = d2c;
            }
        }
    }
    s1 += __shfl_xor(s1, 16); s1 += __shfl_xor(s1, 32);
    if (h == 0) s1p[(size_t)chunk * NN + i] = s1;
    __syncthreads();
    if (tid < 128) {
        const int gi = iG * 128 + tid;
        const unsigned c = ccnt[tid];
        const unsigned cw = umn(c, (unsigned)CAPC);
        const unsigned addv = (c <= (unsigned)CAPC) ? c : (c + 0x10000u);
        unsigned base = atomicAdd(&gcnt[gi], addv) & 0xFFFFu;
        float* dst = candG + (size_t)gi * CAPR;
        for (unsigned s = 0; s < cw; s++) {
            unsigned p = base + s;
            if (p < (unsigned)CAPR) dst[p] = clist[tid][s];
        }
    }
}

// ---------------- density: merged s1 + closed-form s2 = N*sqi + SQ - 2*xi.S ----------------
__global__ __launch_bounds__(256) void k_merge_den(const float* __restrict__ s1p,
                                                   const double* __restrict__ rowpart,
                                                   const uint32_t* __restrict__ xch,
                                                   const float* __restrict__ sqh,
                                                   float* __restrict__ den) {
    __shared__ double Ssh[17];
    const int tid = threadIdx.x;
    if (tid < 17) {
        double t = 0.0;
        for (int b = 0; b < 32; b++) t += rowpart[(size_t)b * 32 + tid];
        Ssh[tid] = t;
    }
    __syncthreads();
    const int i = blockIdx.x * 256 + tid;
    double g1 = 0.0;
#pragma unroll
    for (int c = 0; c < CH2; c++) g1 += (double)s1p[(size_t)c * NN + i];
    double dotS = 0.0;
    {
        const uint4* p = (const uint4*)(xch + (size_t)i * 8);
        uint4 a = p[0], b = p[1];
        uint32_t w[8] = {a.x, a.y, a.z, a.w, b.x, b.y, b.z, b.w};
#pragma unroll
        for (int c = 0; c < 8; c++) {
            f16x2 hh = __builtin_bit_cast(f16x2, w[c]);
            dotS += (double)(float)hh[0] * Ssh[2 * c];
            dotS += (double)(float)hh[1] * Ssh[2 * c + 1];
        }
    }
    double s2 = (double)NN * (double)sqh[i] + Ssh[16] - 2.0 * dotS;
    double var = (s2 - g1 * g1 / (double)NN) / (double)(NN - 1);
    den[i] = (float)sqrt(var > 0.0 ? var : 0.0);
}

// ---------------- global adaptive k ----------------
__global__ __launch_bounds__(1024) void k_adaptk(const float* __restrict__ density,
                                                 int* __restrict__ kout) {
    const int tid = threadIdx.x;
    __shared__ float redf[16];
    __shared__ int redi[16];
    __shared__ float dmax_sh;
    const int wid = tid >> 6, lane = tid & 63;
    float mx = 0.f;
    for (int r = tid; r < NN; r += 1024) mx = fmaxf(mx, density[r]);
#pragma unroll
    for (int off = 1; off < 64; off <<= 1) mx = fmaxf(mx, __shfl_xor(mx, off));
    if (lane == 0) redf[wid] = mx;
    __syncthreads();
    if (tid == 0) {
        float m = redf[0];
        for (int w = 1; w < 16; w++) m = fmaxf(m, redf[w]);
        dmax_sh = m;
    }
    __syncthreads();
    const float dmax = dmax_sh + EPSF;
    int ks = 0;
    for (int r = tid; r < NN; r += 1024) {
        float f = density[r] / dmax;
        float kf = fminf(fmaxf(5.0f + 10.0f * f, 5.0f), 20.0f);
        ks += (int)kf;
    }
#pragma unroll
    for (int off = 1; off < 64; off <<= 1) ks += __shfl_xor(ks, off);
    if (lane == 0) redi[wid] = ks;
    __syncthreads();
    if (tid == 0) {
        int t = 0;
        for (int w = 0; w < 16; w++) t += redi[w];
        float meank = (float)t / (float)NN;
        kout[0] = (int)meank;
    }
}

// ---------------- sigma: k-th smallest d2 per row from compact candidates ----------------
__global__ __launch_bounds__(512) void k_sigma(const unsigned* __restrict__ gcnt,
                                               const float* __restrict__ candG,
                                               const int* __restrict__ kptr,
                                               float* __restrict__ sig2,
                                               unsigned* __restrict__ fb_cnt,
                                               unsigned* __restrict__ fb_list) {
    const int tid = threadIdx.x, wid = tid >> 6, lane = tid & 63;
    const int i = blockIdx.x * 8 + wid;
    const int k = kptr[0];
    const unsigned n = gcnt[i];
    if (n <= (unsigned)CAPR) {
        const float* src = candG + (size_t)i * CAPR;
        float v[6];
#pragma unroll
        for (int c = 0; c < 6; c++)
            v[c] = (lane + 64 * c < (int)n) ? src[lane + 64 * c] : FLT_MAX;
        float wm = 0.f;
        for (int rr = 0; rr < k; rr++) {
            float m = v[0];
#pragma unroll
            for (int c = 1; c < 6; c++) m = fminf(m, v[c]);
            wm = m;
#pragma unroll
            for (int off = 1; off < 64; off <<= 1) wm = fminf(wm, __shfl_xor(wm, off));
            unsigned long long b = __ballot(m == wm);
            if (lane == (int)(__ffsll(b) - 1)) {
                bool done = false;
#pragma unroll
                for (int c = 0; c < 6; c++) {
                    bool hit = !done && (v[c] == wm);
                    v[c] = hit ? FLT_MAX : v[c];
                    done = done || hit;
                }
            }
        }
        if (lane == 0) sig2[i] = wm;
    } else {
        if (lane == 0) {
            unsigned slot = atomicAdd(fb_cnt, 1u);
            fb_list[slot] = (unsigned)i;
        }
    }
}

// ---------------- sigma fallback: exact k-th smallest via block-parallel radix-select ----------------
__global__ __launch_bounds__(512) void k_sigma_fb(const unsigned* __restrict__ fb_cnt,
                                                  const unsigned* __restrict__ fb_list,
                                                  const uint32_t* __restrict__ xch,
                                                  const float* __restrict__ sqh,
                                                  const int* __restrict__ kptr,
                                                  float* __restrict__ sig2) {
    __shared__ unsigned redc[8];
    const int tid = threadIdx.x, wid = tid >> 6, lane = tid & 63;
    const unsigned nfb = fb_cnt[0];
    const int k = kptr[0];
    for (unsigned e = blockIdx.x; e < nfb; e += gridDim.x) {
        const int i = (int)fb_list[e];
        uint32_t xi[8];
        {
            const uint4* p = (const uint4*)(xch + (size_t)i * 8);
            uint4 a = p[0], b = p[1];
            xi[0] = a.x; xi[1] = a.y; xi[2] = a.z; xi[3] = a.w;
            xi[4] = b.x; xi[5] = b.y; xi[6] = b.z; xi[7] = b.w;
        }
        const float sqi = sqh[i];
        unsigned vb[16];
#pragma unroll
        for (int s = 0; s < 16; s++) {
            int j = tid + (s << 9);
            const uint4* q = (const uint4*)(xch + (size_t)j * 8);
            uint4 c0 = q[0], c1 = q[1];
            uint32_t xj[8] = {c0.x, c0.y, c0.z, c0.w, c1.x, c1.y, c1.z, c1.w};
            float dot = 0.f;
#pragma unroll
            for (int c = 0; c < 8; c++) dot = fdot2a(xi[c], xj[c], dot);
            float d2c = fmaxf(fmaf(-2.0f, dot, sqi + sqh[j]), 0.0f);
            vb[s] = __float_as_uint(d2c);
        }
        unsigned prefix = 0;
        for (int bit = 30; bit >= 0; bit--) {
            unsigned trial = prefix | (1u << bit);
            unsigned cnt = 0;
#pragma unroll
            for (int s = 0; s < 16; s++) cnt += (vb[s] < trial) ? 1u : 0u;
#pragma unroll
            for (int off = 1; off < 64; off <<= 1) cnt += (unsigned)__shfl_xor((int)cnt, off);
            if (lane == 0) redc[wid] = cnt;
            __syncthreads();
            unsigned tot = redc[0] + redc[1] + redc[2] + redc[3]
                         + redc[4] + redc[5] + redc[6] + redc[7];
            if (tot < (unsigned)k) prefix = trial;
            __syncthreads();
        }
        if (tid == 0) sig2[i] = __uint_as_float(prefix);
        __syncthreads();
    }
}

// ---------------- drift (MFMA QK + MFMA PV): partial numerator/wsum, [chunk][i] layout ----------------
__global__ __launch_bounds__(512, 8) void k_drift_mfma(const uint32_t* __restrict__ xch,
                                                       const float* __restrict__ sqh,
                                                       const float* __restrict__ sig2,
                                                       float* __restrict__ nump,
                                                       float* __restrict__ wsp) {
    __shared__ uint32_t tileA[8 * 512];    // frag-order, 16KB
    __shared__ uint32_t tileT[16 * 256];   // transposed [d][jpair] +2d rotated, 16KB
    __shared__ float sqs[512];             // 2KB
    const int tid = threadIdx.x, wid = tid >> 6, lane = tid & 63;
    const int r = lane & 15, h = lane >> 4;
    const int iG = blockIdx.x >> 4, chunk = blockIdx.x & 15;
    const int jb = chunk << 9;
    const int i0 = (iG * 8 + wid) << 4;
    const int i = i0 + r;

    const float sg = sig2[i];
    const float nl2 = -1.4426950408889634f / (2.0f * sg + EPSF);
    uint2 bu = *(const uint2*)(xch + (size_t)i * 8 + h * 2);
    f16x4 bf = __builtin_bit_cast(f16x4, bu);
    const float sqi = sqh[i];

    f32x4 acc = {0.f, 0.f, 0.f, 0.f};
    float ws = 0.f;

    {
        int jl = tid;
        const uint4* src = (const uint4*)(xch + (size_t)(jb + jl) * 8);
        uint4 a = src[0], b = src[1];
        uint32_t* base = tileA + ((jl >> 4) * 128 + (jl & 15) * 2);
        *(uint2*)(base)      = make_uint2(a.x, a.y);
        *(uint2*)(base + 32) = make_uint2(a.z, a.w);
        *(uint2*)(base + 64) = make_uint2(b.x, b.y);
        *(uint2*)(base + 96) = make_uint2(b.z, b.w);
        sqs[jl] = sqh[jb + jl];
        if (tid < 256) {
            int jp = tid;
            const uint4* sA = (const uint4*)(xch + (size_t)(jb + 2 * jp) * 8);
            const uint4* sB = (const uint4*)(xch + (size_t)(jb + 2 * jp + 1) * 8);
            uint4 a0 = sA[0], a1 = sA[1], b0 = sB[0], b1 = sB[1];
            uint32_t rA[8] = {a0.x, a0.y, a0.z, a0.w, a1.x, a1.y, a1.z, a1.w};
            uint32_t rB[8] = {b0.x, b0.y, b0.z, b0.w, b1.x, b1.y, b1.z, b1.w};
#pragma unroll
            for (int d = 0; d < 16; d++) {
                uint32_t lo = (d & 1) ? (rA[d >> 1] >> 16) : (rA[d >> 1] & 0xFFFFu);
                uint32_t hi = (d & 1) ? (rB[d >> 1] & 0xFFFF0000u) : (rB[d >> 1] << 16);
                tileT[d * 256 + ((jp + 2 * d) & 255)] = lo | hi;
            }
        }
    }
    __syncthreads();
    for (int jt = 0; jt < 32; jt++) {
        uint2 au = *(const uint2*)(tileA + (jt * 128 + lane * 2));
        f16x4 af = __builtin_bit_cast(f16x4, au);
        f32x4 dot = __builtin_amdgcn_mfma_f32_16x16x16f16(af, bf, (f32x4){0.f, 0.f, 0.f, 0.f}, 0, 0, 0);
        f32x4 sq4 = *(const f32x4*)&sqs[jt * 16 + h * 4];
        float w0, w1, w2, w3;
        {
            float d2, d;
            d2 = fmaf(-2.f, dot[0], sqi + sq4[0]); d = fsqrt(fmaxf(d2, 0.f)); w0 = fexp2(d * nl2);
            d2 = fmaf(-2.f, dot[1], sqi + sq4[1]); d = fsqrt(fmaxf(d2, 0.f)); w1 = fexp2(d * nl2);
            d2 = fmaf(-2.f, dot[2], sqi + sq4[2]); d = fsqrt(fmaxf(d2, 0.f)); w2 = fexp2(d * nl2);
            d2 = fmaf(-2.f, dot[3], sqi + sq4[3]); d = fsqrt(fmaxf(d2, 0.f)); w3 = fexp2(d * nl2);
        }
        ws += (w0 + w1) + (w2 + w3);
        uint2 wp = make_uint2(pkrtz(w0, w1), pkrtz(w2, w3));
        f16x4 wf = __builtin_bit_cast(f16x4, wp);
        int jp0 = jt * 8 + h * 2;
        uint2 tv = *(const uint2*)(tileT + (r * 256 + ((jp0 + 2 * r) & 255)));
        f16x4 btf = __builtin_bit_cast(f16x4, tv);
        acc = __builtin_amdgcn_mfma_f32_16x16x16f16(wf, btf, acc, 0, 0, 0);
    }
    ws += __shfl_xor(ws, 16); ws += __shfl_xor(ws, 32);
    if (h == 0) wsp[(size_t)chunk * NN + i] = ws;
#pragma unroll
    for (int q = 0; q < 4; q++) {
        int irow = i0 + h * 4 + q;
        nump[((size_t)chunk * NN + irow) * 16 + r] = acc[q];
    }
}

// ---------------- fused: merge drift partials + h = xc + step*(drift-xc) + 0.01*noise + col-stats ----------------
__global__ __launch_bounds__(256) void k_hpre_stats(const float* __restrict__ xc,
                                                    const float* __restrict__ nump,
                                                    const float* __restrict__ wsp,
                                                    const float* __restrict__ noise,
                                                    const float* __restrict__ alpha,
                                                    float* __restrict__ hpre,
                                                    double* __restrict__ part) {
    const int i = blockIdx.x * 256 + threadIdx.x;
    const float step = powf(16.0f, -alpha[0]);
    float w = 0.f;
#pragma unroll
    for (int c = 0; c < CH2; c++) w += wsp[(size_t)c * NN + i];   // coalesced
    const float inv = 1.0f / (w + EPSF);
    f4 dr[4] = {{0,0,0,0},{0,0,0,0},{0,0,0,0},{0,0,0,0}};
#pragma unroll
    for (int c = 0; c < CH2; c++) {
        const f4* np = (const f4*)(nump + ((size_t)c * NN + i) * 16);  // 64B/lane contiguous
#pragma unroll
        for (int q = 0; q < 4; q++) {
            f4 v = np[q];
            dr[q].x += v.x; dr[q].y += v.y; dr[q].z += v.z; dr[q].w += v.w;
        }
    }
    const f4* xr = (const f4*)(xc + (size_t)i * DD);
    const f4* nr = (const f4*)(noise + (size_t)i * DD);
    f4* ho = (f4*)(hpre + (size_t)i * DD);
    float h[DD];
#pragma unroll
    for (int q = 0; q < 4; q++) {
        f4 a = xr[q], n = nr[q], o;
        o.x = a.x + step * (dr[q].x * inv - a.x) + n.x * 0.01f;
        o.y = a.y + step * (dr[q].y * inv - a.y) + n.y * 0.01f;
        o.z = a.z + step * (dr[q].z * inv - a.z) + n.z * 0.01f;
        o.w = a.w + step * (dr[q].w * inv - a.w) + n.w * 0.01f;
        ho[q] = o;
        h[4*q+0] = o.x; h[4*q+1] = o.y; h[4*q+2] = o.z; h[4*q+3] = o.w;
    }
    colstat_reduce_store(h, part, blockIdx.x, threadIdx.x);
}

// ---------------- final (fused ratio): out = h * (stdx/(stdh+eps)) + mean ----------------
__global__ __launch_bounds__(256) void k_final(float* __restrict__ h,
                                               const double* __restrict__ part2,
                                               const float* __restrict__ stdx,
                                               const float* __restrict__ meanp) {
    __shared__ __align__(16) float rsh[16];
    __shared__ __align__(16) float msh[16];
    const int tid = threadIdx.x;
    if (tid < 16) {
        double s = 0.0, q = 0.0;
        for (int b = 0; b < 32; b++) {
            s += part2[(size_t)b * 32 + tid];
            q += part2[(size_t)b * 32 + 16 + tid];
        }
        double var = (q - s * s / (double)NN) / (double)(NN - 1);
        float stdh = (float)sqrt(var > 0.0 ? var : 0.0);
        rsh[tid] = stdx[tid] / (stdh + EPSF);
        msh[tid] = meanp[tid];
    }
    __syncthreads();
    const int i = blockIdx.x * 256 + tid;
    f4* hr = (f4*)(h + (size_t)i * DD);
#pragma unroll
    for (int q = 0; q < 4; q++) {
        f4 v = hr[q];
        f4 rv = *(const f4*)&rsh[q * 4];
        f4 mv = *(const f4*)&msh[q * 4];
        v.x = v.x * rv.x + mv.x;
        v.y = v.y * rv.y + mv.y;
        v.z = v.z * rv.z + mv.z;
        v.w = v.w * rv.w + mv.w;
        hr[q] = v;
    }
}

extern "C" void kernel_launch(void* const* d_in, const int* in_sizes, int n_in,
                              void* d_out, int out_size, void* d_ws, size_t ws_size,
                              hipStream_t stream) {
    (void)in_sizes; (void)n_in; (void)out_size; (void)ws_size;
    const float* x = (const float*)d_in[0];
    const float* noise = (const float*)d_in[1];
    const float* alpha = (const float*)d_in[2];
    float* out = (float*)d_out;

    double* part1 = (double*)d_ws;                        // 32*32 dbl
    double* part2 = part1 + 1024;                         // 32*32 dbl
    double* rowpart = part2 + 1024;                       // 32*32 dbl
    float*    xc   = (float*)(rowpart + 1024);            // N*16
    uint32_t* xch  = (uint32_t*)(xc + (size_t)NN * DD);   // N*8
    float*    sqh  = (float*)(xch + (size_t)NN * 8);      // N
    float*    den  = sqh + NN;                            // N
    float*    smlh = den + NN;                            // N*4*15
    float*    thr  = smlh + (size_t)NN * 60;              // N
    float*    s1p  = thr + NN;                            // 16*N
    unsigned* gcnt = (unsigned*)(s1p + (size_t)NN * CH2); // N
    unsigned* fb_cnt = gcnt + NN;                         // 1 (+pad 63)
    unsigned* fb_list = fb_cnt + 64;                      // N
    float*    candG = (float*)(fb_list + NN);             // N*384 (12.6MB)
    float*    sig2 = candG + (size_t)NN * CAPR;           // N
    float*    nump = sig2 + NN;                           // 16*N*16 (8.4MB)
    float*    wsp  = nump + (size_t)NN * CH2 * 16;        // 16*N
    float*    meanp = wsp + (size_t)NN * CH2;             // 16
    float*    stdx  = meanp + DD;                         // 16
    int*      kptr  = (int*)(stdx + DD);                  // 1

    k_stats_part_x<<<32, 256, 0, stream>>>(x, part1);
    k_center<<<32, 256, 0, stream>>>(x, part1, xc, xch, sqh, gcnt, fb_cnt, meanp, stdx);
    k_thresh<<<512, 256, 0, stream>>>(xch, sqh, smlh);
    k_thrmerge<<<32, 256, 0, stream>>>(smlh, xch, sqh, thr, rowpart);
    k_pass1_lean<<<1024, 512, 0, stream>>>(xch, sqh, thr, s1p, gcnt, candG);
    k_merge_den<<<32, 256, 0, stream>>>(s1p, rowpart, xch, sqh, den);
    k_adaptk<<<1, 1024, 0, stream>>>(den, kptr);
    k_sigma<<<1024, 512, 0, stream>>>(gcnt, candG, kptr, sig2, fb_cnt, fb_list);
    k_sigma_fb<<<128, 512, 0, stream>>>(fb_cnt, fb_list, xch, sqh, kptr, sig2);
    k_drift_mfma<<<1024, 512, 0, stream>>>(xch, sqh, sig2, nump, wsp);
    k_hpre_stats<<<32, 256, 0, stream>>>(xc, nump, wsp, noise, alpha, out, part2);
    k_final<<<32, 256, 0, stream>>>(out, part2, stdx, meanp);
}